// Round 6
// baseline (260.229 us; speedup 1.0000x reference)
//
#include <hip/hip_runtime.h>
#include <hip/hip_bf16.h>
#include <string.h>

#define OUT_H 7
#define OUT_W 7
#define FEAT_H 200
#define FEAT_W 200
#define HW_ALL (FEAT_H * FEAT_W)
#define HWB  32      // hw rows per transpose block
#define LSTR 260     // LDS row stride (floats): rows 16B-aligned (260*4=1040), low conflict

__device__ inline unsigned pack2_bf16(float a, float b) {
    __hip_bfloat16 ha = __float2bfloat16(a);
    __hip_bfloat16 hb = __float2bfloat16(b);
    unsigned short ua, ub;
    memcpy(&ua, &ha, 2);
    memcpy(&ub, &hb, 2);
    return (unsigned)ua | ((unsigned)ub << 16);
}

// ---------------- Kernel 1: NCHW fp32 -> NHWC bf16 (v2, UNCHANGED) ----------------
__global__ __launch_bounds__(256) void nchw_to_nhwc_bf16_v2(
    const float* __restrict__ in,     // (B, 256, HW)
    unsigned*    __restrict__ outu,   // (B, HW, 256) bf16, viewed as uints
    int HW)
{
    __shared__ float tile[HWB * LSTR];   // ~33 KB -> 4 blocks/CU
    int hw0 = blockIdx.x * HWB;
    int b   = blockIdx.y;
    const float* inb = in + (size_t)b * 256 * HW + hw0;

    int lane = threadIdx.x & 63;
    int w    = threadIdx.x >> 6;     // wave 0..3 owns 64 channels
    int cg   = lane >> 3;            // 0..7  (channel sub-group)
    int xq   = lane & 7;             // 0..7  (hw quad: 4*xq)
    int hwr  = xq << 2;

#pragma unroll
    for (int cc = 0; cc < 8; ++cc) {
        int c = (w << 6) + (cc << 3) + cg;
        float4 v = *(const float4*)(inb + (size_t)c * HW + hwr);
        tile[(hwr + 0) * LSTR + c] = v.x;
        tile[(hwr + 1) * LSTR + c] = v.y;
        tile[(hwr + 2) * LSTR + c] = v.z;
        tile[(hwr + 3) * LSTR + c] = v.w;
    }
    __syncthreads();

    uint2* ob = (uint2*)outu + ((size_t)b * HW + hw0) * 64;  // 64 uint2 per pixel
    int t = threadIdx.x;
#pragma unroll
    for (int i = 0; i < 8; ++i) {
        int q2  = (i << 8) + t;          // uint2 index in block
        int hr  = q2 >> 6;               // hw row 0..31
        int c0  = (q2 & 63) << 2;        // channel base (multiple of 4)
        float4 v = *(const float4*)&tile[hr * LSTR + c0];
        uint2 o;
        o.x = pack2_bf16(v.x, v.y);
        o.y = pack2_bf16(v.z, v.w);
        ob[q2] = o;
    }
}

// ---------------- Kernel 2: RoIAlign on NHWC bf16 (v3) ----------------
// Block = (roi, channel-half): 1024 blocks (4/CU), 128 channels each.
// Thread t: pg = t>>5 (8 position groups), cq = t&31 (channel quad in half).
// LDS 24.5 KB -> better occupancy than v2's 49 KB.
__global__ __launch_bounds__(256) void roialign_nhwc_v3(
    const uint2* __restrict__ featT2,  // (B, HW, 64) uint2 = 4 bf16 channels
    const int*   __restrict__ rois,    // (N, 5)
    float*       __restrict__ out)     // (N, 256, 49)
{
    __shared__ float acc[128 * OUT_H * OUT_W];   // 24.5 KB
    const int H = FEAT_H, W = FEAT_W;
    int n = blockIdx.x >> 1;
    int h = blockIdx.x & 1;            // channel half: 0 -> c 0..127, 1 -> c 128..255
    const int* r = rois + n * 5;
    int   b   = r[0];
    float x1f = (float)r[1];
    float y1f = (float)r[2];
    float dx  = (float)r[3] - x1f;
    float dy  = (float)r[4] - y1f;

    int t  = threadIdx.x;
    int pg = t >> 5;                   // 0..7 (half-wave uniform)
    int cq = t & 31;                   // channel quad within half
    const uint2* fb = featT2 + (size_t)b * HW_ALL * 64 + (h << 5) + cq;

#define BFLO(u) __uint_as_float((u) << 16)
#define BFHI(u) __uint_as_float((u) & 0xffff0000u)

#pragma unroll
    for (int pi = 0; pi < 7; ++pi) {
        int p = (pi << 3) + pg;
        if (p < 49) {
            int jy = p / 7, jx = p % 7;
            float sy = y1f + ((float)jy * dy) / 6.0f;
            float sx = x1f + ((float)jx * dx) / 6.0f;
            float y0fl = floorf(sy), x0fl = floorf(sx);
            float wy = sy - y0fl,    wx = sx - x0fl;
            int y0  = min(max((int)y0fl, 0), H - 1);
            int y1i = min(y0 + 1, H - 1);
            int x0  = min(max((int)x0fl, 0), W - 1);
            int x1i = min(x0 + 1, W - 1);
            float omwy = 1.0f - wy, omwx = 1.0f - wx;
            float w00 = omwy * omwx, w01 = omwy * wx;
            float w10 = wy * omwx,   w11 = wy * wx;

            const uint2* row0 = fb + (size_t)(y0  * W) * 64;
            const uint2* row1 = fb + (size_t)(y1i * W) * 64;
            uint2 u00 = row0[(size_t)x0  * 64];
            uint2 u01 = row0[(size_t)x1i * 64];
            uint2 u10 = row1[(size_t)x0  * 64];
            uint2 u11 = row1[(size_t)x1i * 64];

            float r0 = BFLO(u00.x)*w00 + BFLO(u01.x)*w01 + BFLO(u10.x)*w10 + BFLO(u11.x)*w11;
            float r1 = BFHI(u00.x)*w00 + BFHI(u01.x)*w01 + BFHI(u10.x)*w10 + BFHI(u11.x)*w11;
            float r2 = BFLO(u00.y)*w00 + BFLO(u01.y)*w01 + BFLO(u10.y)*w10 + BFLO(u11.y)*w11;
            float r3 = BFHI(u00.y)*w00 + BFHI(u01.y)*w01 + BFHI(u10.y)*w10 + BFHI(u11.y)*w11;

            int c0 = cq << 2;          // local channel base 0..124
            acc[(c0 + 0) * 49 + p] = r0;
            acc[(c0 + 1) * 49 + p] = r1;
            acc[(c0 + 2) * 49 + p] = r2;
            acc[(c0 + 3) * 49 + p] = r3;
        }
    }
    __syncthreads();

    // LDS local flat order == out[n, h*128 + cl, p] flat order.
    float* ob = out + (size_t)n * (256 * OUT_H * OUT_W) + (size_t)h * (128 * OUT_H * OUT_W);
    const int total = 128 * OUT_H * OUT_W;   // 6272
    for (int k = t; k < total; k += 256)
        ob[k] = acc[k];
}

// ---------------- Fallback: direct NCHW kernel ----------------
__global__ __launch_bounds__(256) void roialign_direct(
    const float* __restrict__ feat, const int* __restrict__ rois,
    float* __restrict__ out, int C, int total)
{
    int idx = blockIdx.x * blockDim.x + threadIdx.x;
    if (idx >= total) return;
    const int H = FEAT_H, W = FEAT_W;
    int jx = idx % OUT_W;
    int t  = idx / OUT_W;
    int jy = t % OUT_H;
    t /= OUT_H;
    int c = t % C;
    int n = t / C;
    const int* r = rois + n * 5;
    int b = r[0];
    float x1 = (float)r[1], y1 = (float)r[2];
    float x2 = (float)r[3], y2 = (float)r[4];
    float sy = y1 + ((float)jy * (y2 - y1)) / (float)(OUT_H - 1);
    float sx = x1 + ((float)jx * (x2 - x1)) / (float)(OUT_W - 1);
    float y0f = floorf(sy), x0f = floorf(sx);
    float wy = sy - y0f, wx = sx - x0f;
    int y0  = min(max((int)y0f, 0), H - 1);
    int y1i = min(y0 + 1, H - 1);
    int x0  = min(max((int)x0f, 0), W - 1);
    int x1i = min(x0 + 1, W - 1);
    const float* fp = feat + ((size_t)b * C + c) * (size_t)(H * W);
    float v00 = fp[y0  * W + x0 ];
    float v01 = fp[y0  * W + x1i];
    float v10 = fp[y1i * W + x0 ];
    float v11 = fp[y1i * W + x1i];
    float omwy = 1.0f - wy, omwx = 1.0f - wx;
    out[idx] = v00 * omwy * omwx + v01 * omwy * wx
             + v10 * wy   * omwx + v11 * wy   * wx;
}

extern "C" void kernel_launch(void* const* d_in, const int* in_sizes, int n_in,
                              void* d_out, int out_size, void* d_ws, size_t ws_size,
                              hipStream_t stream)
{
    const float* feat = (const float*)d_in[0];
    const int*   rois = (const int*)d_in[1];
    float*       out  = (float*)d_out;

    int N  = in_sizes[1] / 5;                        // 512
    int C  = out_size / (N * OUT_H * OUT_W);         // 256
    int HW = FEAT_H * FEAT_W;                        // 40000
    int B  = in_sizes[0] / (C * HW);                 // 4

    size_t need = (size_t)B * HW * C * sizeof(__hip_bfloat16);  // 82 MB
    if (C == 256 && (HW % HWB) == 0 && ws_size >= need) {
        unsigned* featT = (unsigned*)d_ws;
        dim3 tgrid(HW / HWB, B, 1);
        nchw_to_nhwc_bf16_v2<<<tgrid, 256, 0, stream>>>(feat, featT, HW);
        roialign_nhwc_v3<<<N * 2, 256, 0, stream>>>((const uint2*)featT, rois, out);
    } else {
        int total = out_size;
        roialign_direct<<<(total + 255) / 256, 256, 0, stream>>>(feat, rois, out, C, total);
    }
}